// Round 6
// baseline (211.224 us; speedup 1.0000x reference)
//
#include <hip/hip_runtime.h>
#include <hip/hip_bf16.h>

typedef unsigned short u16;
typedef __attribute__((ext_vector_type(8))) short  bf16x8;
typedef __attribute__((ext_vector_type(4))) float  fx4;

// flat offsets of TT cores in the packed kernel (reference iterates k=3..0 from idx 0)
#define OFF_C0 0       // core for k=3: [8 x 256]   core0[i4][a3*8+o4]
#define OFF_C1 2048    // core for k=2: [256 x 256] core1[i3*32+a3][a2*8+o3]
#define OFF_C2 67584   // core for k=1: [256 x 256] core2[i2*32+a2][a1*8+o2]
#define OFF_C3 133120  // core for k=0: [256 x 8]   core3[i1*32+a1][o1]

static __device__ __forceinline__ u16 f2bf(float f) {
  union { __hip_bfloat16 h; u16 u; } cv;
  cv.h = __float2bfloat16(f);
  return cv.u;
}
static __device__ __forceinline__ float bf2f(u16 u) {
  union { u16 u; __hip_bfloat16 h; } cv;
  cv.u = u;
  return __bfloat162float(cv.h);
}

// fused: blocks [0,8192) convert x fp32->bf16 (8 elems/thread); blocks [8192,8704) build W34T.
__global__ void x_and_w34T(const float* __restrict__ x, u16* __restrict__ xb,
                           const float* __restrict__ ker, float* __restrict__ w34T) {
  if (blockIdx.x < 8192) {
    int t = blockIdx.x * 256 + threadIdx.x;
    const fx4* p = (const fx4*)(x + (size_t)t * 8);
    fx4 v0 = p[0], v1 = p[1];
    u16 tmp[8];
#pragma unroll
    for (int q = 0; q < 4; ++q) tmp[q] = f2bf(v0[q]);
#pragma unroll
    for (int q = 0; q < 4; ++q) tmp[4 + q] = f2bf(v1[q]);
    typedef __attribute__((ext_vector_type(8))) u16 u16x8;
    *(u16x8*)(xb + (size_t)t * 8) = *(const u16x8*)tmp;
  } else {
    int t = (blockIdx.x - 8192) * 256 + threadIdx.x;   // 131072 threads
    int i34 = t & 63, c = t >> 6;
    int a2 = c >> 6, o3 = (c >> 3) & 7, o4 = c & 7;
    int i3 = i34 >> 3, i4 = i34 & 7;
    float s = 0.f;
#pragma unroll 8
    for (int a3 = 0; a3 < 32; ++a3) {
      float k1 = ker[OFF_C1 + (i3 * 32 + a3) * 256 + a2 * 8 + o3];
      float k0 = ker[OFF_C0 + i4 * 256 + a3 * 8 + o4];
      s += k1 * k0;
    }
    w34T[c * 64 + i34] = s;
  }
}

// W234t[(a1*64+o2*8+o3)*8 + o4][i234] = sum_a2 core2[i2*32+a2, a1*8+o2] * W34T[a2*64+o3*8+o4][i34]
__global__ void build_w234t2(const float* __restrict__ ker, const float* __restrict__ w34T,
                             u16* __restrict__ w234t) {
  int t = blockIdx.x * 256 + threadIdx.x;   // 131072 threads
  int i234 = t & 511, g = t >> 9;           // g = a1*8 + o3
  int a1 = g >> 3, o3 = g & 7;
  int i2 = i234 >> 6, i34 = i234 & 63;
  float acc[8][8];
#pragma unroll
  for (int a = 0; a < 8; ++a)
#pragma unroll
    for (int b = 0; b < 8; ++b) acc[a][b] = 0.f;
  for (int a2 = 0; a2 < 32; ++a2) {
    float w[8];
#pragma unroll
    for (int o4 = 0; o4 < 8; ++o4)
      w[o4] = w34T[(a2 * 64 + o3 * 8 + o4) * 64 + i34];
#pragma unroll
    for (int o2 = 0; o2 < 8; ++o2) {
      float c2 = ker[OFF_C2 + (i2 * 32 + a2) * 256 + a1 * 8 + o2];
#pragma unroll
      for (int o4 = 0; o4 < 8; ++o4) acc[o2][o4] += c2 * w[o4];
    }
  }
#pragma unroll
  for (int o2 = 0; o2 < 8; ++o2) {
    int cg = a1 * 64 + o2 * 8 + o3;
#pragma unroll
    for (int o4 = 0; o4 < 8; ++o4)
      w234t[(cg * 8 + o4) * 512 + i234] = f2bf(acc[o2][o4]);
  }
}

// Wt[j,i]: thread owns (j234, i234), reads each w234t element once, computes all 64 (i1,o1).
__global__ void build_wt2(const float* __restrict__ ker, const u16* __restrict__ w234t,
                          u16* __restrict__ wt) {
  int t = blockIdx.x * 256 + threadIdx.x;   // 262144 threads
  int i234 = t & 511, j234 = t >> 9;
  float acc[8][8];
#pragma unroll
  for (int a = 0; a < 8; ++a)
#pragma unroll
    for (int b = 0; b < 8; ++b) acc[a][b] = 0.f;
  for (int a1 = 0; a1 < 32; ++a1) {
    float w = bf2f(w234t[(a1 * 512 + j234) * 512 + i234]);
#pragma unroll
    for (int i1 = 0; i1 < 8; ++i1) {
      const float* c3 = ker + OFF_C3 + (i1 * 32 + a1) * 8;
#pragma unroll
      for (int o1 = 0; o1 < 8; ++o1) acc[i1][o1] += c3[o1] * w;
    }
  }
#pragma unroll
  for (int o1 = 0; o1 < 8; ++o1)
#pragma unroll
    for (int i1 = 0; i1 < 8; ++i1)
      wt[(size_t)(o1 * 512 + j234) * 4096 + i1 * 512 + i234] = f2bf(acc[i1][o1]);
}

__device__ __forceinline__ void gld16(const u16* g, u16* l) {
  __builtin_amdgcn_global_load_lds((const __attribute__((address_space(1))) void*)g,
                                   (__attribute__((address_space(3))) void*)l, 16, 0, 0);
}

// C[4096,4096] = A * Bt^T + bias (bf16 in, fp32 out).
// BM=128, BN=256, BK=32, 256 threads (4 waves 2Mx2N), per-wave 64x128 (4x8 frags 16x16x32).
// LDS: 3 buffers x (A 8KB + B 16KB) = 72 KB -> 2 independent blocks/CU (anti-phase barrier
// domains overlap LDS-read and MFMA pipes without intra-block schedule perfection).
// Free-run loop: 12 ds_read + 6 gld16(stage t+2) + 32 MFMA + vmcnt(6) + one barrier.
// XOR slot swizzle (inverse-swizzled global source + swizzled ds_read) - measured 0 conflicts.
__global__ __launch_bounds__(256, 2) void gemm_half(const u16* __restrict__ A, const u16* __restrict__ Bt,
                                                    const float* __restrict__ bias, float* __restrict__ C) {
  __shared__ __align__(16) u16 sh[36864];  // A bufs [0,12288) elems, B bufs [12288,36864)

  const int tid = threadIdx.x;
  const int lane = tid & 63;
  const int wave = tid >> 6;
  const int wm = wave >> 1, wn = wave & 1;
  const int fr = lane & 15, fg = lane >> 4;

  // XCD-aware block swizzle (512 blocks, 512%8==0)
  const int bid = blockIdx.x;
  const int wg = (bid & 7) * 64 + (bid >> 3);
  const int bm = (wg >> 4) * 128, bn = (wg & 15) * 256;

  // staging: 16-row chunks of 1024B; lane -> row chunk*16 + (lane>>2), slot lane&3.
  // LDS dest linear; global source slot pre-swizzled s ^ ((row>>1)&3).
  const int lq = lane >> 2, ls = lane & 3;
  size_t agA[2], agB[4];
#pragma unroll
  for (int L = 0; L < 2; ++L) {
    const int row = (wave * 2 + L) * 16 + lq;     // 0..127
    agA[L] = (size_t)(bm + row) * 4096 + ((ls ^ ((row >> 1) & 3)) * 8);
  }
#pragma unroll
  for (int L = 0; L < 4; ++L) {
    const int row = (wave * 4 + L) * 16 + lq;     // 0..255
    agB[L] = (size_t)(bn + row) * 4096 + ((ls ^ ((row >> 1) & 3)) * 8);
  }
  u16* const ldA0 = sh + (wave * 2) * 512;        // + buf*4096
  u16* const ldB0 = sh + 12288 + (wave * 4) * 512;  // + buf*8192

  // fragment read element-offsets within a buffer: off = R*32 + ((fg ^ ((R>>1)&3))*8)
  int aoff[4], boff[8];
#pragma unroll
  for (int m = 0; m < 4; ++m) {
    const int R = wm * 64 + m * 16 + fr;
    aoff[m] = R * 32 + ((fg ^ ((R >> 1) & 3)) * 8);
  }
#pragma unroll
  for (int n = 0; n < 8; ++n) {
    const int R = wn * 128 + n * 16 + fr;
    boff[n] = R * 32 + ((fg ^ ((R >> 1) & 3)) * 8);
  }

  fx4 acc[4][8];
#pragma unroll
  for (int m = 0; m < 4; ++m)
#pragma unroll
    for (int n = 0; n < 8; ++n) acc[m][n] = (fx4){0.f, 0.f, 0.f, 0.f};

#define STAGE(buf, t) do { const size_t k_ = (size_t)(((t) & 127) * 32); \
    u16* a_ = ldA0 + (buf) * 4096; u16* b_ = ldB0 + (buf) * 8192; \
    gld16(A + agA[0] + k_, a_); \
    gld16(A + agA[1] + k_, a_ + 512); \
    gld16(Bt + agB[0] + k_, b_); \
    gld16(Bt + agB[1] + k_, b_ + 512); \
    gld16(Bt + agB[2] + k_, b_ + 1024); \
    gld16(Bt + agB[3] + k_, b_ + 1536); } while (0)

  // prologue: stage tiles 0,1 (12 loads); wait tile 0 (retire 6)
  STAGE(0, 0);
  STAGE(1, 1);
  asm volatile("s_waitcnt vmcnt(6)" ::: "memory");
  __builtin_amdgcn_s_barrier();

  int p = 0;   // buf of tile t
  for (int t = 0; t < 128; ++t) {
    const int ps = p + 2 >= 3 ? p - 1 : p + 2;   // buf of tile t+2
    const u16* Ap = sh + p * 4096;
    const u16* Bp = sh + 12288 + p * 8192;

    bf16x8 av[4], bv[8];
#pragma unroll
    for (int m = 0; m < 4; ++m) av[m] = *(const bf16x8*)(Ap + aoff[m]);
#pragma unroll
    for (int n = 0; n < 8; ++n) bv[n] = *(const bf16x8*)(Bp + boff[n]);

    STAGE(ps, t + 2);   // wrapped k at tail: stages unused-but-harmless data

    __builtin_amdgcn_s_setprio(1);
#pragma unroll
    for (int m = 0; m < 4; ++m)
#pragma unroll
      for (int n = 0; n < 8; ++n)
        acc[m][n] = __builtin_amdgcn_mfma_f32_16x16x32_bf16(av[m], bv[n], acc[m][n], 0, 0, 0);
    __builtin_amdgcn_s_setprio(0);

    // retire tile t+1's 6 loads (needed next iteration); keep t+2's 6 in flight.
    asm volatile("s_waitcnt vmcnt(6)" ::: "memory");
    __builtin_amdgcn_s_barrier();
    p = p + 1 >= 3 ? 0 : p + 1;
  }

  // epilogue: C/D layout col=lane&15, row=(lane>>4)*4+reg  [m89]
  const int crow0 = bm + wm * 64 + fg * 4;
  const int ccol0 = bn + wn * 128 + fr;
#pragma unroll
  for (int n = 0; n < 8; ++n) {
    const int col = ccol0 + n * 16;
    const float bvl = bias[col];
#pragma unroll
    for (int m = 0; m < 4; ++m) {
      const int r0 = crow0 + m * 16;
#pragma unroll
      for (int q = 0; q < 4; ++q)
        C[(size_t)(r0 + q) * 4096 + col] = acc[m][n][q] + bvl;
    }
  }
#undef STAGE
}

extern "C" void kernel_launch(void* const* d_in, const int* in_sizes, int n_in,
                              void* d_out, int out_size, void* d_ws, size_t ws_size,
                              hipStream_t stream) {
  const float* x    = (const float*)d_in[0];
  const float* ker  = (const float*)d_in[1];
  const float* bias = (const float*)d_in[2];
  float* out = (float*)d_out;

  char* ws = (char*)d_ws;
  u16*  xb    = (u16*)ws;                      // 32 MB  bf16 x
  u16*  wt    = (u16*)(ws + 33554432);         // 32 MB  bf16 W^T
  u16*  w234t = (u16*)(ws + 67108864);         // 16 MB  bf16 W234^T
  float* w34T = (float*)(ws + 83886080);       // 512 KB fp32 W34 transposed

  x_and_w34T  <<<8704, 256, 0, stream>>>(x, xb, ker, w34T);
  build_w234t2<<<512, 256, 0, stream>>>(ker, w34T, w234t);
  build_wt2   <<<1024, 256, 0, stream>>>(ker, w234t, wt);
  gemm_half   <<<512, 256, 0, stream>>>(xb, wt, bias, out);
}